// Round 1
// baseline (620.389 us; speedup 1.0000x reference)
//
#include <hip/hip_runtime.h>
#include <math.h>

// Problem constants: n=2, c=256, t=2, h=64, w=64; HB=WB=16, bn_h=bn_w=4;
// NHEAD=8, d=32. Stage1: L1=32 tokens x B1=512 batch. Stage2: L2=512 x B2=32.
// Token id m1 = l1*512 + b1, l1=(t*4+bh)*4+bw, b1=n*256+i*16+j.
// Token id m2 = l2*32 + b2,  l2=t*256+i*16+j,  b2=n*16+bh*4+bw.
// Input/out layout [n,c,t,h,w]: flat = n*2097152 + c*8192 + t*4096 + h*64 + w.

#define SCALE_D32 0.17677669529663687f  // 1/sqrt(32)

// ---------------- pack: [n,c,t,h,w] -> token-major [16384,256] ----------------
// Writes Xp = pos, Xq = q+pos, Xk = k+pos, Xv = v.
__global__ __launch_bounds__(256) void pack_kernel(
    const float* __restrict__ q, const float* __restrict__ k,
    const float* __restrict__ v, const float* __restrict__ pos,
    float* __restrict__ Xp, float* __restrict__ Xq,
    float* __restrict__ Xk, float* __restrict__ Xv) {
  __shared__ float tP[64][65];
  __shared__ float tX[64][65];
  int b = blockIdx.x;
  int cb = b & 3;
  int h  = (b >> 2) & 63;
  int nt = b >> 8;
  int n = nt >> 1, t = nt & 1;
  int c0 = cb * 64;
  int bh = h >> 4, ii = h & 15;
  long inbase = (long)n * 2097152 + (long)t * 4096 + (long)h * 64;
  int tx = threadIdx.x & 63;
  int ty = threadIdx.x >> 6;  // 0..3

  // load pos + q tiles (lanes across w, coalesced)
  for (int cc = ty; cc < 64; cc += 4) {
    long a = inbase + (long)(c0 + cc) * 8192 + tx;
    tP[cc][tx] = pos[a];
    tX[cc][tx] = q[a];
  }
  __syncthreads();
  // store (lanes across c, coalesced 256B rows)
  for (int ww = ty; ww < 64; ww += 4) {
    int bw = ww >> 4, j = ww & 15;
    int m1 = (((t * 4 + bh) * 4 + bw) * 512) + n * 256 + ii * 16 + j;
    long o = (long)m1 * 256 + c0 + tx;
    float pv = tP[tx][ww];
    Xp[o] = pv;
    Xq[o] = tX[tx][ww] + pv;
  }
  __syncthreads();
  for (int cc = ty; cc < 64; cc += 4) {
    long a = inbase + (long)(c0 + cc) * 8192 + tx;
    tX[cc][tx] = k[a];
  }
  __syncthreads();
  for (int ww = ty; ww < 64; ww += 4) {
    int bw = ww >> 4, j = ww & 15;
    int m1 = (((t * 4 + bh) * 4 + bw) * 512) + n * 256 + ii * 16 + j;
    long o = (long)m1 * 256 + c0 + tx;
    Xk[o] = tX[tx][ww] + tP[tx][ww];
  }
  __syncthreads();
  for (int cc = ty; cc < 64; cc += 4) {
    long a = inbase + (long)(c0 + cc) * 8192 + tx;
    tX[cc][tx] = v[a];
  }
  __syncthreads();
  for (int ww = ty; ww < 64; ww += 4) {
    int bw = ww >> 4, j = ww & 15;
    int m1 = (((t * 4 + bh) * 4 + bw) * 512) + n * 256 + ii * 16 + j;
    long o = (long)m1 * 256 + c0 + tx;
    Xv[o] = tX[tx][ww];
  }
}

// ---------------- fp32 TN GEMM: C[M,256] = A[M,256] @ W[256,256]^T + b -------
// grid (M/64, N/64), block 256, 64x64 tile, 4x4 per thread, K staged LDS-transposed.
__global__ __launch_bounds__(256) void gemm_tn(
    const float* __restrict__ A, const float* __restrict__ Wt,
    const float* __restrict__ bias, float* __restrict__ Cmat) {
  __shared__ float As[16][68];
  __shared__ float Ws[16][68];
  int m0 = blockIdx.x * 64;
  int n0 = blockIdx.y * 64;
  int tid = threadIdx.x;
  int tm = tid >> 4, tn = tid & 15;
  int lrow = tid >> 2;  // 0..63
  int lseg = tid & 3;   // k-seg (4 floats)
  float acc[4][4] = {};
  const float* Aip = A + (long)(m0 + lrow) * 256 + lseg * 4;
  const float* Wip = Wt + (long)(n0 + lrow) * 256 + lseg * 4;
  for (int kb = 0; kb < 16; ++kb) {
    float4 av = *(const float4*)(Aip + kb * 16);
    float4 wv = *(const float4*)(Wip + kb * 16);
    As[lseg * 4 + 0][lrow] = av.x;
    As[lseg * 4 + 1][lrow] = av.y;
    As[lseg * 4 + 2][lrow] = av.z;
    As[lseg * 4 + 3][lrow] = av.w;
    Ws[lseg * 4 + 0][lrow] = wv.x;
    Ws[lseg * 4 + 1][lrow] = wv.y;
    Ws[lseg * 4 + 2][lrow] = wv.z;
    Ws[lseg * 4 + 3][lrow] = wv.w;
    __syncthreads();
#pragma unroll
    for (int kk = 0; kk < 16; ++kk) {
      float4 a4 = *(const float4*)&As[kk][tm * 4];
      float4 w4 = *(const float4*)&Ws[kk][tn * 4];
      float ar[4] = {a4.x, a4.y, a4.z, a4.w};
      float wr[4] = {w4.x, w4.y, w4.z, w4.w};
#pragma unroll
      for (int i2 = 0; i2 < 4; ++i2)
#pragma unroll
        for (int j2 = 0; j2 < 4; ++j2)
          acc[i2][j2] = fmaf(ar[i2], wr[j2], acc[i2][j2]);
    }
    __syncthreads();
  }
  float4 bv = *(const float4*)&bias[n0 + tn * 4];
  float br[4] = {bv.x, bv.y, bv.z, bv.w};
#pragma unroll
  for (int i2 = 0; i2 < 4; ++i2) {
    float4 r;
    r.x = acc[i2][0] + br[0];
    r.y = acc[i2][1] + br[1];
    r.z = acc[i2][2] + br[2];
    r.w = acc[i2][3] + br[3];
    *(float4*)&Cmat[(long)(m0 + tm * 4 + i2) * 256 + n0 + tn * 4] = r;
  }
}

// ---------------- stage-1 attention: L=32, d=32, per-wave (b1, head) --------
__global__ __launch_bounds__(64) void attn1_kernel(
    const float* __restrict__ Q1, const float* __restrict__ K1,
    const float* __restrict__ V1, float* __restrict__ O1) {
  __shared__ float Qs[32][36];
  __shared__ float Ks[32][36];
  __shared__ float Vs[32][36];
  int b1 = blockIdx.x >> 3;
  int hh = blockIdx.x & 7;
  int lane = threadIdx.x;
  for (int idx = lane; idx < 256; idx += 64) {
    int row = idx >> 3, seg = idx & 7;
    long a = ((long)row * 512 + b1) * 256 + hh * 32 + seg * 4;
    *(float4*)&Qs[row][seg * 4] = *(const float4*)&Q1[a];
    *(float4*)&Ks[row][seg * 4] = *(const float4*)&K1[a];
    *(float4*)&Vs[row][seg * 4] = *(const float4*)&V1[a];
  }
  __syncthreads();
  int lq = lane & 31, half = lane >> 5;
  float qreg[32];
#pragma unroll
  for (int s8 = 0; s8 < 8; ++s8) {
    float4 qv = *(const float4*)&Qs[lq][s8 * 4];
    qreg[s8 * 4 + 0] = qv.x;
    qreg[s8 * 4 + 1] = qv.y;
    qreg[s8 * 4 + 2] = qv.z;
    qreg[s8 * 4 + 3] = qv.w;
  }
  float sc[16];
#pragma unroll
  for (int z = 0; z < 16; ++z) {
    int lk = half * 16 + z;
    float d = 0.f;
#pragma unroll
    for (int s8 = 0; s8 < 8; ++s8) {
      float4 kv = *(const float4*)&Ks[lk][s8 * 4];
      d += qreg[s8 * 4 + 0] * kv.x + qreg[s8 * 4 + 1] * kv.y +
           qreg[s8 * 4 + 2] * kv.z + qreg[s8 * 4 + 3] * kv.w;
    }
    sc[z] = d * SCALE_D32;
  }
  float mymax = sc[0];
#pragma unroll
  for (int z = 1; z < 16; ++z) mymax = fmaxf(mymax, sc[z]);
  float omax = __shfl_xor(mymax, 32, 64);
  float gm = fmaxf(mymax, omax);
  float ssum = 0.f;
#pragma unroll
  for (int z = 0; z < 16; ++z) {
    sc[z] = __expf(sc[z] - gm);
    ssum += sc[z];
  }
  float osum = __shfl_xor(ssum, 32, 64);
  float inv = 1.f / (ssum + osum);
  float o[32] = {};
#pragma unroll
  for (int z = 0; z < 16; ++z) {
    int lk = half * 16 + z;
    float p = sc[z];
#pragma unroll
    for (int s8 = 0; s8 < 8; ++s8) {
      float4 vv = *(const float4*)&Vs[lk][s8 * 4];
      o[s8 * 4 + 0] += p * vv.x;
      o[s8 * 4 + 1] += p * vv.y;
      o[s8 * 4 + 2] += p * vv.z;
      o[s8 * 4 + 3] += p * vv.w;
    }
  }
#pragma unroll
  for (int dd = 0; dd < 32; ++dd) o[dd] += __shfl_xor(o[dd], 32, 64);
  long ob = ((long)lq * 512 + b1) * 256 + hh * 32;
  if (half == 0) {
#pragma unroll
    for (int s4 = 0; s4 < 4; ++s4) {
      float4 r;
      r.x = o[s4 * 4 + 0] * inv;
      r.y = o[s4 * 4 + 1] * inv;
      r.z = o[s4 * 4 + 2] * inv;
      r.w = o[s4 * 4 + 3] * inv;
      *(float4*)&O1[ob + s4 * 4] = r;
    }
  } else {
#pragma unroll
    for (int s4 = 0; s4 < 4; ++s4) {
      float4 r;
      r.x = o[16 + s4 * 4 + 0] * inv;
      r.y = o[16 + s4 * 4 + 1] * inv;
      r.z = o[16 + s4 * 4 + 2] * inv;
      r.w = o[16 + s4 * 4 + 3] * inv;
      *(float4*)&O1[ob + 16 + s4 * 4] = r;
    }
  }
}

// ---------------- stage-2 attention: flash, L=512, d=32 ---------------------
// grid: b2(32) x hh(8) x qblk(8) = 2048; block 256 (16x16 threads, 4x4 S frag).
__global__ __launch_bounds__(256) void attn2_kernel(
    const float* __restrict__ Q2, const float* __restrict__ K2,
    const float* __restrict__ V2, float* __restrict__ O2) {
  __shared__ float Qs[64][36];
  __shared__ float Ks[64][36];
  __shared__ float Vs[64][36];
  __shared__ float Ps[64][68];  // P transposed: [lk][r]
  int bid = blockIdx.x;
  int qblk = bid & 7;
  int hh = (bid >> 3) & 7;
  int b2 = bid >> 6;
  int tid = threadIdx.x;
  int tm = tid >> 4, tn = tid & 15;
  for (int idx = tid; idx < 512; idx += 256) {
    int row = idx >> 3, seg = idx & 7;
    long a = ((long)(qblk * 64 + row) * 32 + b2) * 256 + hh * 32 + seg * 4;
    *(float4*)&Qs[row][seg * 4] = *(const float4*)&Q2[a];
  }
  float mi[4], li[4], oacc[4][2];
#pragma unroll
  for (int i2 = 0; i2 < 4; ++i2) {
    mi[i2] = -1e30f;
    li[i2] = 0.f;
    oacc[i2][0] = 0.f;
    oacc[i2][1] = 0.f;
  }
  for (int kb = 0; kb < 8; ++kb) {
    __syncthreads();  // protect Ks/Vs/Ps from previous iteration readers
    for (int idx = tid; idx < 512; idx += 256) {
      int row = idx >> 3, seg = idx & 7;
      long a = ((long)(kb * 64 + row) * 32 + b2) * 256 + hh * 32 + seg * 4;
      *(float4*)&Ks[row][seg * 4] = *(const float4*)&K2[a];
      *(float4*)&Vs[row][seg * 4] = *(const float4*)&V2[a];
    }
    __syncthreads();
    float s[4][4] = {};
#pragma unroll
    for (int s8 = 0; s8 < 8; ++s8) {
      float4 aq[4], bk[4];
#pragma unroll
      for (int i2 = 0; i2 < 4; ++i2) aq[i2] = *(const float4*)&Qs[tm * 4 + i2][s8 * 4];
#pragma unroll
      for (int j2 = 0; j2 < 4; ++j2) bk[j2] = *(const float4*)&Ks[tn * 4 + j2][s8 * 4];
#pragma unroll
      for (int i2 = 0; i2 < 4; ++i2) {
#pragma unroll
        for (int j2 = 0; j2 < 4; ++j2) {
          s[i2][j2] += aq[i2].x * bk[j2].x + aq[i2].y * bk[j2].y +
                       aq[i2].z * bk[j2].z + aq[i2].w * bk[j2].w;
        }
      }
    }
#pragma unroll
    for (int i2 = 0; i2 < 4; ++i2) {
      float rm = -1e30f;
#pragma unroll
      for (int j2 = 0; j2 < 4; ++j2) {
        s[i2][j2] *= SCALE_D32;
        rm = fmaxf(rm, s[i2][j2]);
      }
      rm = fmaxf(rm, __shfl_xor(rm, 1, 64));
      rm = fmaxf(rm, __shfl_xor(rm, 2, 64));
      rm = fmaxf(rm, __shfl_xor(rm, 4, 64));
      rm = fmaxf(rm, __shfl_xor(rm, 8, 64));
      float mnew = fmaxf(mi[i2], rm);
      float al = __expf(mi[i2] - mnew);
      float p0 = __expf(s[i2][0] - mnew);
      float p1 = __expf(s[i2][1] - mnew);
      float p2 = __expf(s[i2][2] - mnew);
      float p3 = __expf(s[i2][3] - mnew);
      float rs = p0 + p1 + p2 + p3;
      rs += __shfl_xor(rs, 1, 64);
      rs += __shfl_xor(rs, 2, 64);
      rs += __shfl_xor(rs, 4, 64);
      rs += __shfl_xor(rs, 8, 64);
      li[i2] = li[i2] * al + rs;
      mi[i2] = mnew;
      oacc[i2][0] *= al;
      oacc[i2][1] *= al;
      Ps[tn * 4 + 0][tm * 4 + i2] = p0;
      Ps[tn * 4 + 1][tm * 4 + i2] = p1;
      Ps[tn * 4 + 2][tm * 4 + i2] = p2;
      Ps[tn * 4 + 3][tm * 4 + i2] = p3;
    }
    __syncthreads();
#pragma unroll 8
    for (int lk = 0; lk < 64; ++lk) {
      float4 pc = *(const float4*)&Ps[lk][tm * 4];
      float2 vv = *(const float2*)&Vs[lk][tn * 2];
      oacc[0][0] += pc.x * vv.x;
      oacc[0][1] += pc.x * vv.y;
      oacc[1][0] += pc.y * vv.x;
      oacc[1][1] += pc.y * vv.y;
      oacc[2][0] += pc.z * vv.x;
      oacc[2][1] += pc.z * vv.y;
      oacc[3][0] += pc.w * vv.x;
      oacc[3][1] += pc.w * vv.y;
    }
  }
#pragma unroll
  for (int i2 = 0; i2 < 4; ++i2) {
    float inv = 1.f / li[i2];
    float2 r;
    r.x = oacc[i2][0] * inv;
    r.y = oacc[i2][1] * inv;
    long a = ((long)(qblk * 64 + tm * 4 + i2) * 32 + b2) * 256 + hh * 32 + tn * 2;
    *(float2*)&O2[a] = r;
  }
}

// ---------------- row-permute m1 -> m2, fold +pos for stage-2 q/k input -----
__global__ __launch_bounds__(256) void perm12_kernel(
    const float4* __restrict__ V1o, const float4* __restrict__ Xp,
    float4* __restrict__ X2, float4* __restrict__ V2in) {
  int g = blockIdx.x * 256 + threadIdx.x;  // 0 .. 1048575 (float4 units)
  int m1 = g >> 6, seg = g & 63;
  int l1 = m1 >> 9, b1 = m1 & 511;
  int t = l1 >> 4, bh = (l1 >> 2) & 3, bw = l1 & 3;
  int n = b1 >> 8, ii = (b1 >> 4) & 15, j = b1 & 15;
  int l2 = t * 256 + ii * 16 + j;
  int b2 = n * 16 + bh * 4 + bw;
  int m2 = l2 * 32 + b2;
  float4 v = V1o[g];
  float4 p = Xp[g];
  float4 x;
  x.x = v.x + p.x;
  x.y = v.y + p.y;
  x.z = v.z + p.z;
  x.w = v.w + p.w;
  X2[m2 * 64 + seg] = x;
  V2in[m2 * 64 + seg] = v;
}

// ---------------- unpack: [16384,256] (m2-order) -> out [n,c,t,h,w] ---------
__global__ __launch_bounds__(256) void unpack_kernel(
    const float* __restrict__ Y, float* __restrict__ out) {
  __shared__ float tl[64][65];
  int b = blockIdx.x;
  int cb = b & 3;
  int h = (b >> 2) & 63;
  int nt = b >> 8;
  int n = nt >> 1, t = nt & 1;
  int c0 = cb * 64;
  int bh = h >> 4, ii = h & 15;
  int tx = threadIdx.x & 63;
  int ty = threadIdx.x >> 6;
  for (int ww = ty; ww < 64; ww += 4) {
    int bw = ww >> 4, j = ww & 15;
    int l2 = t * 256 + ii * 16 + j;
    int b2 = n * 16 + bh * 4 + bw;
    int m2 = l2 * 32 + b2;
    tl[tx][ww] = Y[(long)m2 * 256 + c0 + tx];
  }
  __syncthreads();
  long ob = (long)n * 2097152 + (long)t * 4096 + (long)h * 64 + tx;
  for (int cc = ty; cc < 64; cc += 4) {
    out[ob + (long)(c0 + cc) * 8192] = tl[cc][tx];
  }
}

extern "C" void kernel_launch(void* const* d_in, const int* in_sizes, int n_in,
                              void* d_out, int out_size, void* d_ws, size_t ws_size,
                              hipStream_t stream) {
  const float* q      = (const float*)d_in[0];
  const float* k      = (const float*)d_in[1];
  const float* v      = (const float*)d_in[2];
  const float* pos    = (const float*)d_in[3];
  const float* wl_in  = (const float*)d_in[4];
  const float* bl_in  = (const float*)d_in[5];
  const float* wl_out = (const float*)d_in[6];
  const float* bl_out = (const float*)d_in[7];
  const float* ws_in  = (const float*)d_in[8];
  const float* bs_in  = (const float*)d_in[9];
  const float* ws_out = (const float*)d_in[10];
  const float* bs_out = (const float*)d_in[11];
  float* out = (float*)d_out;
  float* ws = (float*)d_ws;
  const size_t SL = 4194304;  // floats per 16 MB slot (16384 x 256)
  float* s0 = ws;            // Xp -> (dead after perm12) -> O2
  float* s1 = ws + SL;       // Xq -> O1 -> V2
  float* s2 = ws + 2 * SL;   // Xk -> V1o -> Yfinal
  float* s3 = ws + 3 * SL;   // Xv -> X2 -> O2
  float* s4 = ws + 4 * SL;   // Q1 -> V2in
  float* s5 = ws + 5 * SL;   // K1 -> Q2
  float* s6 = ws + 6 * SL;   // V1 -> K2

  pack_kernel<<<1024, 256, 0, stream>>>(q, k, v, pos, s0, s1, s2, s3);

  dim3 gg(256, 4);
  gemm_tn<<<gg, 256, 0, stream>>>(s1, wl_in,          bl_in,       s4);  // Q1
  gemm_tn<<<gg, 256, 0, stream>>>(s2, wl_in + 65536,  bl_in + 256, s5);  // K1
  gemm_tn<<<gg, 256, 0, stream>>>(s3, wl_in + 131072, bl_in + 512, s6);  // V1

  attn1_kernel<<<4096, 64, 0, stream>>>(s4, s5, s6, s1);                 // O1 -> s1
  gemm_tn<<<gg, 256, 0, stream>>>(s1, wl_out, bl_out, s2);               // V1o -> s2

  perm12_kernel<<<4096, 256, 0, stream>>>((const float4*)s2, (const float4*)s0,
                                          (float4*)s3, (float4*)s4);     // X2->s3, v2->s4

  gemm_tn<<<gg, 256, 0, stream>>>(s3, ws_in,          bs_in,       s5);  // Q2
  gemm_tn<<<gg, 256, 0, stream>>>(s3, ws_in + 65536,  bs_in + 256, s6);  // K2
  gemm_tn<<<gg, 256, 0, stream>>>(s4, ws_in + 131072, bs_in + 512, s1);  // V2

  attn2_kernel<<<2048, 256, 0, stream>>>(s5, s6, s1, s3);                // O2 -> s3
  gemm_tn<<<gg, 256, 0, stream>>>(s3, ws_out, bs_out, s2);               // Yfinal -> s2

  unpack_kernel<<<1024, 256, 0, stream>>>(s2, out);
}

// Round 2
// 537.445 us; speedup vs baseline: 1.1543x; 1.1543x over previous
//
#include <hip/hip_runtime.h>
#include <math.h>

// Problem constants: n=2, c=256, t=2, h=64, w=64; HB=WB=16, bn_h=bn_w=4;
// NHEAD=8, d=32. Stage1: L1=32 tokens x B1=512 batch. Stage2: L2=512 x B2=32.
// Token id m1 = l1*512 + b1, l1=(t*4+bh)*4+bw, b1=n*256+i*16+j.
// Token id m2 = l2*32 + b2,  l2=t*256+i*16+j,  b2=n*16+bh*4+bw.
// Input/out layout [n,c,t,h,w]: flat = n*2097152 + c*8192 + t*4096 + h*64 + w.

#define SCALE_D32 0.17677669529663687f  // 1/sqrt(32)

typedef short short8 __attribute__((ext_vector_type(8)));   // 8 bf16 = 4 VGPRs (MFMA A/B frag)
typedef short short4v __attribute__((ext_vector_type(4)));  // 4 bf16 = 8B
typedef float floatx4 __attribute__((ext_vector_type(4)));  // MFMA C/D frag

__device__ __forceinline__ short f2bf(float f) {
  union { float f; unsigned u; } x;
  x.f = f;
  unsigned r = x.u + 0x7fffu + ((x.u >> 16) & 1u);  // round-to-nearest-even
  return (short)(r >> 16);
}

// ---------------- pack: [n,c,t,h,w] -> token-major [16384,256] ----------------
// Writes Xp = pos, Xq = q+pos, Xk = k+pos, Xv = v.
__global__ __launch_bounds__(256) void pack_kernel(
    const float* __restrict__ q, const float* __restrict__ k,
    const float* __restrict__ v, const float* __restrict__ pos,
    float* __restrict__ Xp, float* __restrict__ Xq,
    float* __restrict__ Xk, float* __restrict__ Xv) {
  __shared__ float tP[64][65];
  __shared__ float tX[64][65];
  int b = blockIdx.x;
  int cb = b & 3;
  int h  = (b >> 2) & 63;
  int nt = b >> 8;
  int n = nt >> 1, t = nt & 1;
  int c0 = cb * 64;
  int bh = h >> 4, ii = h & 15;
  long inbase = (long)n * 2097152 + (long)t * 4096 + (long)h * 64;
  int tx = threadIdx.x & 63;
  int ty = threadIdx.x >> 6;  // 0..3

  for (int cc = ty; cc < 64; cc += 4) {
    long a = inbase + (long)(c0 + cc) * 8192 + tx;
    tP[cc][tx] = pos[a];
    tX[cc][tx] = q[a];
  }
  __syncthreads();
  for (int ww = ty; ww < 64; ww += 4) {
    int bw = ww >> 4, j = ww & 15;
    int m1 = (((t * 4 + bh) * 4 + bw) * 512) + n * 256 + ii * 16 + j;
    long o = (long)m1 * 256 + c0 + tx;
    float pv = tP[tx][ww];
    Xp[o] = pv;
    Xq[o] = tX[tx][ww] + pv;
  }
  __syncthreads();
  for (int cc = ty; cc < 64; cc += 4) {
    long a = inbase + (long)(c0 + cc) * 8192 + tx;
    tX[cc][tx] = k[a];
  }
  __syncthreads();
  for (int ww = ty; ww < 64; ww += 4) {
    int bw = ww >> 4, j = ww & 15;
    int m1 = (((t * 4 + bh) * 4 + bw) * 512) + n * 256 + ii * 16 + j;
    long o = (long)m1 * 256 + c0 + tx;
    Xk[o] = tX[tx][ww] + tP[tx][ww];
  }
  __syncthreads();
  for (int cc = ty; cc < 64; cc += 4) {
    long a = inbase + (long)(c0 + cc) * 8192 + tx;
    tX[cc][tx] = v[a];
  }
  __syncthreads();
  for (int ww = ty; ww < 64; ww += 4) {
    int bw = ww >> 4, j = ww & 15;
    int m1 = (((t * 4 + bh) * 4 + bw) * 512) + n * 256 + ii * 16 + j;
    long o = (long)m1 * 256 + c0 + tx;
    Xv[o] = tX[tx][ww];
  }
}

// ---------------- bf16 MFMA TN GEMM: C[M,256] = A[M,256] @ W[256,256]^T + b --
// A, W fp32 in global; converted to bf16 (RNE) during LDS staging; fp32 acc.
// grid (M/128, 256/64), block 256 = 4 waves (2x2), wave tile 64x32.
// MFMA 16x16x32_bf16: A-frag = A[m=lane&15][k=quad*8+j] (8 contiguous k),
// B-frag = W[n=lane&15][k=quad*8+j]; C/D: col=lane&15, row=quad*4+reg.
__global__ __launch_bounds__(256) void gemm_mfma(
    const float* __restrict__ A, const float* __restrict__ Wt,
    const float* __restrict__ bias, float* __restrict__ Cmat) {
  __shared__ short As[128][72];  // 128 rows x 64 k, +8 pad (144B row, 16B-aligned)
  __shared__ short Ws[64][72];
  int m0 = blockIdx.x * 128;
  int n0 = blockIdx.y * 64;
  int tid = threadIdx.x;
  int lane = tid & 63;
  int wave = tid >> 6;
  int wm = wave >> 1;  // 0..1 -> 64-row half
  int wn = wave & 1;   // 0..1 -> 32-col half
  int l15 = lane & 15;
  int quad = lane >> 4;

  int srow = tid >> 4;   // 0..15 (staging row within pass)
  int scol4 = tid & 15;  // float4 index within 64-float row chunk

  floatx4 acc[4][2];
#pragma unroll
  for (int mt = 0; mt < 4; ++mt)
#pragma unroll
    for (int nt = 0; nt < 2; ++nt)
      acc[mt][nt] = (floatx4)(0.f);

  for (int kb = 0; kb < 4; ++kb) {
    int k0 = kb * 64;
    if (kb) __syncthreads();  // protect LDS from previous iteration readers
    // stage A: 128 rows x 64 floats, 8 passes of 16 rows
#pragma unroll
    for (int p = 0; p < 8; ++p) {
      int row = p * 16 + srow;
      float4 av = *(const float4*)(A + (long)(m0 + row) * 256 + k0 + scol4 * 4);
      short4v sv;
      sv.x = f2bf(av.x); sv.y = f2bf(av.y); sv.z = f2bf(av.z); sv.w = f2bf(av.w);
      *(short4v*)&As[row][scol4 * 4] = sv;
    }
    // stage W: 64 rows x 64 floats, 4 passes
#pragma unroll
    for (int p = 0; p < 4; ++p) {
      int row = p * 16 + srow;
      float4 wv = *(const float4*)(Wt + (long)(n0 + row) * 256 + k0 + scol4 * 4);
      short4v sv;
      sv.x = f2bf(wv.x); sv.y = f2bf(wv.y); sv.z = f2bf(wv.z); sv.w = f2bf(wv.w);
      *(short4v*)&Ws[row][scol4 * 4] = sv;
    }
    __syncthreads();
#pragma unroll
    for (int ks = 0; ks < 2; ++ks) {
      short8 af[4], bf[2];
#pragma unroll
      for (int mt = 0; mt < 4; ++mt)
        af[mt] = *(const short8*)&As[wm * 64 + mt * 16 + l15][ks * 32 + quad * 8];
#pragma unroll
      for (int nt = 0; nt < 2; ++nt)
        bf[nt] = *(const short8*)&Ws[wn * 32 + nt * 16 + l15][ks * 32 + quad * 8];
#pragma unroll
      for (int mt = 0; mt < 4; ++mt)
#pragma unroll
        for (int nt = 0; nt < 2; ++nt)
          acc[mt][nt] = __builtin_amdgcn_mfma_f32_16x16x32_bf16(
              af[mt], bf[nt], acc[mt][nt], 0, 0, 0);
    }
  }
  float b0 = bias[n0 + wn * 32 + l15];
  float b1 = bias[n0 + wn * 32 + 16 + l15];
#pragma unroll
  for (int mt = 0; mt < 4; ++mt) {
#pragma unroll
    for (int r = 0; r < 4; ++r) {
      int row = m0 + wm * 64 + mt * 16 + quad * 4 + r;
      long base = (long)row * 256 + n0 + wn * 32 + l15;
      Cmat[base] = acc[mt][0][r] + b0;
      Cmat[base + 16] = acc[mt][1][r] + b1;
    }
  }
}

// ---------------- stage-1 attention: L=32, d=32, per-wave (b1, head) --------
__global__ __launch_bounds__(64) void attn1_kernel(
    const float* __restrict__ Q1, const float* __restrict__ K1,
    const float* __restrict__ V1, float* __restrict__ O1) {
  __shared__ float Qs[32][36];
  __shared__ float Ks[32][36];
  __shared__ float Vs[32][36];
  int b1 = blockIdx.x >> 3;
  int hh = blockIdx.x & 7;
  int lane = threadIdx.x;
  for (int idx = lane; idx < 256; idx += 64) {
    int row = idx >> 3, seg = idx & 7;
    long a = ((long)row * 512 + b1) * 256 + hh * 32 + seg * 4;
    *(float4*)&Qs[row][seg * 4] = *(const float4*)&Q1[a];
    *(float4*)&Ks[row][seg * 4] = *(const float4*)&K1[a];
    *(float4*)&Vs[row][seg * 4] = *(const float4*)&V1[a];
  }
  __syncthreads();
  int lq = lane & 31, half = lane >> 5;
  float qreg[32];
#pragma unroll
  for (int s8 = 0; s8 < 8; ++s8) {
    float4 qv = *(const float4*)&Qs[lq][s8 * 4];
    qreg[s8 * 4 + 0] = qv.x;
    qreg[s8 * 4 + 1] = qv.y;
    qreg[s8 * 4 + 2] = qv.z;
    qreg[s8 * 4 + 3] = qv.w;
  }
  float sc[16];
#pragma unroll
  for (int z = 0; z < 16; ++z) {
    int lk = half * 16 + z;
    float d = 0.f;
#pragma unroll
    for (int s8 = 0; s8 < 8; ++s8) {
      float4 kv = *(const float4*)&Ks[lk][s8 * 4];
      d += qreg[s8 * 4 + 0] * kv.x + qreg[s8 * 4 + 1] * kv.y +
           qreg[s8 * 4 + 2] * kv.z + qreg[s8 * 4 + 3] * kv.w;
    }
    sc[z] = d * SCALE_D32;
  }
  float mymax = sc[0];
#pragma unroll
  for (int z = 1; z < 16; ++z) mymax = fmaxf(mymax, sc[z]);
  float omax = __shfl_xor(mymax, 32, 64);
  float gm = fmaxf(mymax, omax);
  float ssum = 0.f;
#pragma unroll
  for (int z = 0; z < 16; ++z) {
    sc[z] = __expf(sc[z] - gm);
    ssum += sc[z];
  }
  float osum = __shfl_xor(ssum, 32, 64);
  float inv = 1.f / (ssum + osum);
  float o[32] = {};
#pragma unroll
  for (int z = 0; z < 16; ++z) {
    int lk = half * 16 + z;
    float p = sc[z];
#pragma unroll
    for (int s8 = 0; s8 < 8; ++s8) {
      float4 vv = *(const float4*)&Vs[lk][s8 * 4];
      o[s8 * 4 + 0] += p * vv.x;
      o[s8 * 4 + 1] += p * vv.y;
      o[s8 * 4 + 2] += p * vv.z;
      o[s8 * 4 + 3] += p * vv.w;
    }
  }
#pragma unroll
  for (int dd = 0; dd < 32; ++dd) o[dd] += __shfl_xor(o[dd], 32, 64);
  long ob = ((long)lq * 512 + b1) * 256 + hh * 32;
  if (half == 0) {
#pragma unroll
    for (int s4 = 0; s4 < 4; ++s4) {
      float4 r;
      r.x = o[s4 * 4 + 0] * inv;
      r.y = o[s4 * 4 + 1] * inv;
      r.z = o[s4 * 4 + 2] * inv;
      r.w = o[s4 * 4 + 3] * inv;
      *(float4*)&O1[ob + s4 * 4] = r;
    }
  } else {
#pragma unroll
    for (int s4 = 0; s4 < 4; ++s4) {
      float4 r;
      r.x = o[16 + s4 * 4 + 0] * inv;
      r.y = o[16 + s4 * 4 + 1] * inv;
      r.z = o[16 + s4 * 4 + 2] * inv;
      r.w = o[16 + s4 * 4 + 3] * inv;
      *(float4*)&O1[ob + 16 + s4 * 4] = r;
    }
  }
}

// ---------------- stage-2 attention: flash, L=512, d=32 ---------------------
// grid: b2(32) x hh(8) x qblk(8) = 2048; block 256 (16x16 threads, 4x4 S frag).
__global__ __launch_bounds__(256) void attn2_kernel(
    const float* __restrict__ Q2, const float* __restrict__ K2,
    const float* __restrict__ V2, float* __restrict__ O2) {
  __shared__ float Qs[64][36];
  __shared__ float Ks[64][36];
  __shared__ float Vs[64][36];
  __shared__ float Ps[64][68];  // P transposed: [lk][r]
  int bid = blockIdx.x;
  int qblk = bid & 7;
  int hh = (bid >> 3) & 7;
  int b2 = bid >> 6;
  int tid = threadIdx.x;
  int tm = tid >> 4, tn = tid & 15;
  for (int idx = tid; idx < 512; idx += 256) {
    int row = idx >> 3, seg = idx & 7;
    long a = ((long)(qblk * 64 + row) * 32 + b2) * 256 + hh * 32 + seg * 4;
    *(float4*)&Qs[row][seg * 4] = *(const float4*)&Q2[a];
  }
  float mi[4], li[4], oacc[4][2];
#pragma unroll
  for (int i2 = 0; i2 < 4; ++i2) {
    mi[i2] = -1e30f;
    li[i2] = 0.f;
    oacc[i2][0] = 0.f;
    oacc[i2][1] = 0.f;
  }
  for (int kb = 0; kb < 8; ++kb) {
    __syncthreads();
    for (int idx = tid; idx < 512; idx += 256) {
      int row = idx >> 3, seg = idx & 7;
      long a = ((long)(kb * 64 + row) * 32 + b2) * 256 + hh * 32 + seg * 4;
      *(float4*)&Ks[row][seg * 4] = *(const float4*)&K2[a];
      *(float4*)&Vs[row][seg * 4] = *(const float4*)&V2[a];
    }
    __syncthreads();
    float s[4][4] = {};
#pragma unroll
    for (int s8 = 0; s8 < 8; ++s8) {
      float4 aq[4], bk[4];
#pragma unroll
      for (int i2 = 0; i2 < 4; ++i2) aq[i2] = *(const float4*)&Qs[tm * 4 + i2][s8 * 4];
#pragma unroll
      for (int j2 = 0; j2 < 4; ++j2) bk[j2] = *(const float4*)&Ks[tn * 4 + j2][s8 * 4];
#pragma unroll
      for (int i2 = 0; i2 < 4; ++i2) {
#pragma unroll
        for (int j2 = 0; j2 < 4; ++j2) {
          s[i2][j2] += aq[i2].x * bk[j2].x + aq[i2].y * bk[j2].y +
                       aq[i2].z * bk[j2].z + aq[i2].w * bk[j2].w;
        }
      }
    }
#pragma unroll
    for (int i2 = 0; i2 < 4; ++i2) {
      float rm = -1e30f;
#pragma unroll
      for (int j2 = 0; j2 < 4; ++j2) {
        s[i2][j2] *= SCALE_D32;
        rm = fmaxf(rm, s[i2][j2]);
      }
      rm = fmaxf(rm, __shfl_xor(rm, 1, 64));
      rm = fmaxf(rm, __shfl_xor(rm, 2, 64));
      rm = fmaxf(rm, __shfl_xor(rm, 4, 64));
      rm = fmaxf(rm, __shfl_xor(rm, 8, 64));
      float mnew = fmaxf(mi[i2], rm);
      float al = __expf(mi[i2] - mnew);
      float p0 = __expf(s[i2][0] - mnew);
      float p1 = __expf(s[i2][1] - mnew);
      float p2 = __expf(s[i2][2] - mnew);
      float p3 = __expf(s[i2][3] - mnew);
      float rs = p0 + p1 + p2 + p3;
      rs += __shfl_xor(rs, 1, 64);
      rs += __shfl_xor(rs, 2, 64);
      rs += __shfl_xor(rs, 4, 64);
      rs += __shfl_xor(rs, 8, 64);
      li[i2] = li[i2] * al + rs;
      mi[i2] = mnew;
      oacc[i2][0] *= al;
      oacc[i2][1] *= al;
      Ps[tn * 4 + 0][tm * 4 + i2] = p0;
      Ps[tn * 4 + 1][tm * 4 + i2] = p1;
      Ps[tn * 4 + 2][tm * 4 + i2] = p2;
      Ps[tn * 4 + 3][tm * 4 + i2] = p3;
    }
    __syncthreads();
#pragma unroll 8
    for (int lk = 0; lk < 64; ++lk) {
      float4 pc = *(const float4*)&Ps[lk][tm * 4];
      float2 vv = *(const float2*)&Vs[lk][tn * 2];
      oacc[0][0] += pc.x * vv.x;
      oacc[0][1] += pc.x * vv.y;
      oacc[1][0] += pc.y * vv.x;
      oacc[1][1] += pc.y * vv.y;
      oacc[2][0] += pc.z * vv.x;
      oacc[2][1] += pc.z * vv.y;
      oacc[3][0] += pc.w * vv.x;
      oacc[3][1] += pc.w * vv.y;
    }
  }
#pragma unroll
  for (int i2 = 0; i2 < 4; ++i2) {
    float inv = 1.f / li[i2];
    float2 r;
    r.x = oacc[i2][0] * inv;
    r.y = oacc[i2][1] * inv;
    long a = ((long)(qblk * 64 + tm * 4 + i2) * 32 + b2) * 256 + hh * 32 + tn * 2;
    *(float2*)&O2[a] = r;
  }
}

// ---------------- row-permute m1 -> m2, fold +pos for stage-2 q/k input -----
__global__ __launch_bounds__(256) void perm12_kernel(
    const float4* __restrict__ V1o, const float4* __restrict__ Xp,
    float4* __restrict__ X2, float4* __restrict__ V2in) {
  int g = blockIdx.x * 256 + threadIdx.x;  // 0 .. 1048575 (float4 units)
  int m1 = g >> 6, seg = g & 63;
  int l1 = m1 >> 9, b1 = m1 & 511;
  int t = l1 >> 4, bh = (l1 >> 2) & 3, bw = l1 & 3;
  int n = b1 >> 8, ii = (b1 >> 4) & 15, j = b1 & 15;
  int l2 = t * 256 + ii * 16 + j;
  int b2 = n * 16 + bh * 4 + bw;
  int m2 = l2 * 32 + b2;
  float4 v = V1o[g];
  float4 p = Xp[g];
  float4 x;
  x.x = v.x + p.x;
  x.y = v.y + p.y;
  x.z = v.z + p.z;
  x.w = v.w + p.w;
  X2[m2 * 64 + seg] = x;
  V2in[m2 * 64 + seg] = v;
}

// ---------------- unpack: [16384,256] (m2-order) -> out [n,c,t,h,w] ---------
__global__ __launch_bounds__(256) void unpack_kernel(
    const float* __restrict__ Y, float* __restrict__ out) {
  __shared__ float tl[64][65];
  int b = blockIdx.x;
  int cb = b & 3;
  int h = (b >> 2) & 63;
  int nt = b >> 8;
  int n = nt >> 1, t = nt & 1;
  int c0 = cb * 64;
  int bh = h >> 4, ii = h & 15;
  int tx = threadIdx.x & 63;
  int ty = threadIdx.x >> 6;
  for (int ww = ty; ww < 64; ww += 4) {
    int bw = ww >> 4, j = ww & 15;
    int l2 = t * 256 + ii * 16 + j;
    int b2 = n * 16 + bh * 4 + bw;
    int m2 = l2 * 32 + b2;
    tl[tx][ww] = Y[(long)m2 * 256 + c0 + tx];
  }
  __syncthreads();
  long ob = (long)n * 2097152 + (long)t * 4096 + (long)h * 64 + tx;
  for (int cc = ty; cc < 64; cc += 4) {
    out[ob + (long)(c0 + cc) * 8192] = tl[cc][tx];
  }
}

extern "C" void kernel_launch(void* const* d_in, const int* in_sizes, int n_in,
                              void* d_out, int out_size, void* d_ws, size_t ws_size,
                              hipStream_t stream) {
  const float* q      = (const float*)d_in[0];
  const float* k      = (const float*)d_in[1];
  const float* v      = (const float*)d_in[2];
  const float* pos    = (const float*)d_in[3];
  const float* wl_in  = (const float*)d_in[4];
  const float* bl_in  = (const float*)d_in[5];
  const float* wl_out = (const float*)d_in[6];
  const float* bl_out = (const float*)d_in[7];
  const float* ws_in  = (const float*)d_in[8];
  const float* bs_in  = (const float*)d_in[9];
  const float* ws_out = (const float*)d_in[10];
  const float* bs_out = (const float*)d_in[11];
  float* out = (float*)d_out;
  float* ws = (float*)d_ws;
  const size_t SL = 4194304;  // floats per 16 MB slot (16384 x 256)
  float* s0 = ws;            // Xp -> (dead after perm12) -> O2
  float* s1 = ws + SL;       // Xq -> O1 -> V2
  float* s2 = ws + 2 * SL;   // Xk -> V1o -> Yfinal
  float* s3 = ws + 3 * SL;   // Xv -> X2 -> O2
  float* s4 = ws + 4 * SL;   // Q1 -> V2in
  float* s5 = ws + 5 * SL;   // K1 -> Q2
  float* s6 = ws + 6 * SL;   // V1 -> K2

  pack_kernel<<<1024, 256, 0, stream>>>(q, k, v, pos, s0, s1, s2, s3);

  dim3 gg(128, 4);  // 128 M-blocks x 4 N-blocks, tile 128x64
  gemm_mfma<<<gg, 256, 0, stream>>>(s1, wl_in,          bl_in,       s4);  // Q1
  gemm_mfma<<<gg, 256, 0, stream>>>(s2, wl_in + 65536,  bl_in + 256, s5);  // K1
  gemm_mfma<<<gg, 256, 0, stream>>>(s3, wl_in + 131072, bl_in + 512, s6);  // V1

  attn1_kernel<<<4096, 64, 0, stream>>>(s4, s5, s6, s1);                 // O1 -> s1
  gemm_mfma<<<gg, 256, 0, stream>>>(s1, wl_out, bl_out, s2);             // V1o -> s2

  perm12_kernel<<<4096, 256, 0, stream>>>((const float4*)s2, (const float4*)s0,
                                          (float4*)s3, (float4*)s4);     // X2->s3, v2->s4

  gemm_mfma<<<gg, 256, 0, stream>>>(s3, ws_in,          bs_in,       s5);  // Q2
  gemm_mfma<<<gg, 256, 0, stream>>>(s3, ws_in + 65536,  bs_in + 256, s6);  // K2
  gemm_mfma<<<gg, 256, 0, stream>>>(s4, ws_in + 131072, bs_in + 512, s1);  // V2

  attn2_kernel<<<2048, 256, 0, stream>>>(s5, s6, s1, s3);                // O2 -> s3
  gemm_mfma<<<gg, 256, 0, stream>>>(s3, ws_out, bs_out, s2);             // Yfinal -> s2

  unpack_kernel<<<1024, 256, 0, stream>>>(s2, out);
}

// Round 3
// 397.246 us; speedup vs baseline: 1.5617x; 1.3529x over previous
//
#include <hip/hip_runtime.h>
#include <math.h>

// Problem constants: n=2, c=256, t=2, h=64, w=64; HB=WB=16, bn_h=bn_w=4;
// NHEAD=8, d=32. Stage1: L1=32 tokens x B1=512 batch. Stage2: L2=512 x B2=32.
// Token id m1 = l1*512 + b1, l1=(t*4+bh)*4+bw, b1=n*256+i*16+j.
// Token id m2 = l2*32 + b2,  l2=t*256+i*16+j,  b2=n*16+bh*4+bw.
// Input/out layout [n,c,t,h,w]: flat = n*2097152 + c*8192 + t*4096 + h*64 + w.

#define SCALE_D32 0.17677669529663687f  // 1/sqrt(32)

typedef short short8 __attribute__((ext_vector_type(8)));   // 8 bf16 = 4 VGPRs (MFMA A/B frag)
typedef short short4v __attribute__((ext_vector_type(4)));  // 4 bf16 = 8B
typedef float floatx4 __attribute__((ext_vector_type(4)));  // MFMA C/D frag

__device__ __forceinline__ short f2bf(float f) {
  union { float f; unsigned u; } x;
  x.f = f;
  unsigned r = x.u + 0x7fffu + ((x.u >> 16) & 1u);  // round-to-nearest-even
  return (short)(r >> 16);
}

// ---------------- pack: [n,c,t,h,w] -> token-major [16384,256] ----------------
__global__ __launch_bounds__(256) void pack_kernel(
    const float* __restrict__ q, const float* __restrict__ k,
    const float* __restrict__ v, const float* __restrict__ pos,
    float* __restrict__ Xp, float* __restrict__ Xq,
    float* __restrict__ Xk, float* __restrict__ Xv) {
  __shared__ float tP[64][65];
  __shared__ float tX[64][65];
  int b = blockIdx.x;
  int cb = b & 3;
  int h  = (b >> 2) & 63;
  int nt = b >> 8;
  int n = nt >> 1, t = nt & 1;
  int c0 = cb * 64;
  int bh = h >> 4, ii = h & 15;
  long inbase = (long)n * 2097152 + (long)t * 4096 + (long)h * 64;
  int tx = threadIdx.x & 63;
  int ty = threadIdx.x >> 6;  // 0..3

  for (int cc = ty; cc < 64; cc += 4) {
    long a = inbase + (long)(c0 + cc) * 8192 + tx;
    tP[cc][tx] = pos[a];
    tX[cc][tx] = q[a];
  }
  __syncthreads();
  for (int ww = ty; ww < 64; ww += 4) {
    int bw = ww >> 4, j = ww & 15;
    int m1 = (((t * 4 + bh) * 4 + bw) * 512) + n * 256 + ii * 16 + j;
    long o = (long)m1 * 256 + c0 + tx;
    float pv = tP[tx][ww];
    Xp[o] = pv;
    Xq[o] = tX[tx][ww] + pv;
  }
  __syncthreads();
  for (int cc = ty; cc < 64; cc += 4) {
    long a = inbase + (long)(c0 + cc) * 8192 + tx;
    tX[cc][tx] = k[a];
  }
  __syncthreads();
  for (int ww = ty; ww < 64; ww += 4) {
    int bw = ww >> 4, j = ww & 15;
    int m1 = (((t * 4 + bh) * 4 + bw) * 512) + n * 256 + ii * 16 + j;
    long o = (long)m1 * 256 + c0 + tx;
    Xk[o] = tX[tx][ww] + tP[tx][ww];
  }
  __syncthreads();
  for (int cc = ty; cc < 64; cc += 4) {
    long a = inbase + (long)(c0 + cc) * 8192 + tx;
    tX[cc][tx] = v[a];
  }
  __syncthreads();
  for (int ww = ty; ww < 64; ww += 4) {
    int bw = ww >> 4, j = ww & 15;
    int m1 = (((t * 4 + bh) * 4 + bw) * 512) + n * 256 + ii * 16 + j;
    long o = (long)m1 * 256 + c0 + tx;
    Xv[o] = tX[tx][ww];
  }
}

// ---------------- bf16 MFMA TN GEMM: C[M,256] = A[M,256] @ W[256,256]^T + b --
__global__ __launch_bounds__(256) void gemm_mfma(
    const float* __restrict__ A, const float* __restrict__ Wt,
    const float* __restrict__ bias, float* __restrict__ Cmat) {
  __shared__ short As[128][72];
  __shared__ short Ws[64][72];
  int m0 = blockIdx.x * 128;
  int n0 = blockIdx.y * 64;
  int tid = threadIdx.x;
  int lane = tid & 63;
  int wave = tid >> 6;
  int wm = wave >> 1;
  int wn = wave & 1;
  int l15 = lane & 15;
  int quad = lane >> 4;

  int srow = tid >> 4;
  int scol4 = tid & 15;

  floatx4 acc[4][2];
#pragma unroll
  for (int mt = 0; mt < 4; ++mt)
#pragma unroll
    for (int nt = 0; nt < 2; ++nt)
      acc[mt][nt] = (floatx4)(0.f);

  for (int kb = 0; kb < 4; ++kb) {
    int k0 = kb * 64;
    if (kb) __syncthreads();
#pragma unroll
    for (int p = 0; p < 8; ++p) {
      int row = p * 16 + srow;
      float4 av = *(const float4*)(A + (long)(m0 + row) * 256 + k0 + scol4 * 4);
      short4v sv;
      sv.x = f2bf(av.x); sv.y = f2bf(av.y); sv.z = f2bf(av.z); sv.w = f2bf(av.w);
      *(short4v*)&As[row][scol4 * 4] = sv;
    }
#pragma unroll
    for (int p = 0; p < 4; ++p) {
      int row = p * 16 + srow;
      float4 wv = *(const float4*)(Wt + (long)(n0 + row) * 256 + k0 + scol4 * 4);
      short4v sv;
      sv.x = f2bf(wv.x); sv.y = f2bf(wv.y); sv.z = f2bf(wv.z); sv.w = f2bf(wv.w);
      *(short4v*)&Ws[row][scol4 * 4] = sv;
    }
    __syncthreads();
#pragma unroll
    for (int ks = 0; ks < 2; ++ks) {
      short8 af[4], bf[2];
#pragma unroll
      for (int mt = 0; mt < 4; ++mt)
        af[mt] = *(const short8*)&As[wm * 64 + mt * 16 + l15][ks * 32 + quad * 8];
#pragma unroll
      for (int nt = 0; nt < 2; ++nt)
        bf[nt] = *(const short8*)&Ws[wn * 32 + nt * 16 + l15][ks * 32 + quad * 8];
#pragma unroll
      for (int mt = 0; mt < 4; ++mt)
#pragma unroll
        for (int nt = 0; nt < 2; ++nt)
          acc[mt][nt] = __builtin_amdgcn_mfma_f32_16x16x32_bf16(
              af[mt], bf[nt], acc[mt][nt], 0, 0, 0);
    }
  }
  float b0 = bias[n0 + wn * 32 + l15];
  float b1 = bias[n0 + wn * 32 + 16 + l15];
#pragma unroll
  for (int mt = 0; mt < 4; ++mt) {
#pragma unroll
    for (int r = 0; r < 4; ++r) {
      int row = m0 + wm * 64 + mt * 16 + quad * 4 + r;
      long base = (long)row * 256 + n0 + wn * 32 + l15;
      Cmat[base] = acc[mt][0][r] + b0;
      Cmat[base + 16] = acc[mt][1][r] + b1;
    }
  }
}

// ---------------- stage-1 attention: L=32, d=32, per-wave (b1, head) --------
__global__ __launch_bounds__(64) void attn1_kernel(
    const float* __restrict__ Q1, const float* __restrict__ K1,
    const float* __restrict__ V1, float* __restrict__ O1) {
  __shared__ float Qs[32][36];
  __shared__ float Ks[32][36];
  __shared__ float Vs[32][36];
  int b1 = blockIdx.x >> 3;
  int hh = blockIdx.x & 7;
  int lane = threadIdx.x;
  for (int idx = lane; idx < 256; idx += 64) {
    int row = idx >> 3, seg = idx & 7;
    long a = ((long)row * 512 + b1) * 256 + hh * 32 + seg * 4;
    *(float4*)&Qs[row][seg * 4] = *(const float4*)&Q1[a];
    *(float4*)&Ks[row][seg * 4] = *(const float4*)&K1[a];
    *(float4*)&Vs[row][seg * 4] = *(const float4*)&V1[a];
  }
  __syncthreads();
  int lq = lane & 31, half = lane >> 5;
  float qreg[32];
#pragma unroll
  for (int s8 = 0; s8 < 8; ++s8) {
    float4 qv = *(const float4*)&Qs[lq][s8 * 4];
    qreg[s8 * 4 + 0] = qv.x;
    qreg[s8 * 4 + 1] = qv.y;
    qreg[s8 * 4 + 2] = qv.z;
    qreg[s8 * 4 + 3] = qv.w;
  }
  float sc[16];
#pragma unroll
  for (int z = 0; z < 16; ++z) {
    int lk = half * 16 + z;
    float d = 0.f;
#pragma unroll
    for (int s8 = 0; s8 < 8; ++s8) {
      float4 kv = *(const float4*)&Ks[lk][s8 * 4];
      d += qreg[s8 * 4 + 0] * kv.x + qreg[s8 * 4 + 1] * kv.y +
           qreg[s8 * 4 + 2] * kv.z + qreg[s8 * 4 + 3] * kv.w;
    }
    sc[z] = d * SCALE_D32;
  }
  float mymax = sc[0];
#pragma unroll
  for (int z = 1; z < 16; ++z) mymax = fmaxf(mymax, sc[z]);
  float omax = __shfl_xor(mymax, 32, 64);
  float gm = fmaxf(mymax, omax);
  float ssum = 0.f;
#pragma unroll
  for (int z = 0; z < 16; ++z) {
    sc[z] = __expf(sc[z] - gm);
    ssum += sc[z];
  }
  float osum = __shfl_xor(ssum, 32, 64);
  float inv = 1.f / (ssum + osum);
  float o[32] = {};
#pragma unroll
  for (int z = 0; z < 16; ++z) {
    int lk = half * 16 + z;
    float p = sc[z];
#pragma unroll
    for (int s8 = 0; s8 < 8; ++s8) {
      float4 vv = *(const float4*)&Vs[lk][s8 * 4];
      o[s8 * 4 + 0] += p * vv.x;
      o[s8 * 4 + 1] += p * vv.y;
      o[s8 * 4 + 2] += p * vv.z;
      o[s8 * 4 + 3] += p * vv.w;
    }
  }
#pragma unroll
  for (int dd = 0; dd < 32; ++dd) o[dd] += __shfl_xor(o[dd], 32, 64);
  long ob = ((long)lq * 512 + b1) * 256 + hh * 32;
  if (half == 0) {
#pragma unroll
    for (int s4 = 0; s4 < 4; ++s4) {
      float4 r;
      r.x = o[s4 * 4 + 0] * inv;
      r.y = o[s4 * 4 + 1] * inv;
      r.z = o[s4 * 4 + 2] * inv;
      r.w = o[s4 * 4 + 3] * inv;
      *(float4*)&O1[ob + s4 * 4] = r;
    }
  } else {
#pragma unroll
    for (int s4 = 0; s4 < 4; ++s4) {
      float4 r;
      r.x = o[16 + s4 * 4 + 0] * inv;
      r.y = o[16 + s4 * 4 + 1] * inv;
      r.z = o[16 + s4 * 4 + 2] * inv;
      r.w = o[16 + s4 * 4 + 3] * inv;
      *(float4*)&O1[ob + 16 + s4 * 4] = r;
    }
  }
}

// ---------------- stage-2 attention: MFMA flash, L=512, d=32 ----------------
// grid: b2(32) x hh(8) x qblk(8) = 2048; block 256 = 4 waves, 16 Q-rows/wave.
// Q resident as 16x16x32 A-frag (d=32=K). 64-key chunks: 4 S-MFMAs + online
// softmax (fp32, C-layout) + P->LDS (bf16, key-permuted pi(k)=4*(k&15)+(k>>4)
// so each lane packs 4 adjacent cols) + 4 PV-MFMAs (V^T staged with same pi).
__global__ __launch_bounds__(256) void attn2_mfma(
    const float* __restrict__ Q2, const float* __restrict__ K2,
    const float* __restrict__ V2, float* __restrict__ O2) {
  __shared__ short Ks[64][40];      // [key][d]  row 80B (16B-mult)
  __shared__ short Vt[32][72];      // [d][pi(key)] row 144B (16B-mult)
  __shared__ short Pw[4][16][72];   // per-wave [q][pi(key)]
  int bid = blockIdx.x;
  int qblk = bid & 7;
  int hh = (bid >> 3) & 7;
  int b2 = bid >> 6;
  int tid = threadIdx.x;
  int wave = tid >> 6, lane = tid & 63;
  int l15 = lane & 15, quad = lane >> 4;

  // Q fragment: m = l15 -> q row; k = quad*8+j -> d
  short8 qf;
  {
    long tok = (long)(qblk * 64 + wave * 16 + l15) * 32 + b2;
    const float* qp = Q2 + tok * 256 + hh * 32 + quad * 8;
    float4 a = *(const float4*)qp;
    float4 b = *(const float4*)(qp + 4);
    qf[0] = f2bf(a.x); qf[1] = f2bf(a.y); qf[2] = f2bf(a.z); qf[3] = f2bf(a.w);
    qf[4] = f2bf(b.x); qf[5] = f2bf(b.y); qf[6] = f2bf(b.z); qf[7] = f2bf(b.w);
  }
  floatx4 Oa = (floatx4)(0.f), Ob = (floatx4)(0.f);
  float mi[4], li[4];
#pragma unroll
  for (int r = 0; r < 4; ++r) { mi[r] = -1e30f; li[r] = 0.f; }

  // staging maps
  int skey = tid >> 2;          // K: 0..63
  int sd0 = (tid & 3) * 8;      // K: d-offset
  int vkey = lane;              // V: key = lane, d0 = wave*8 (write full cols)
  int vd0 = wave * 8;
  int vcol = (vkey & 15) * 4 + (vkey >> 4);  // pi(key)

  for (int kb = 0; kb < 8; ++kb) {
    if (kb) __syncthreads();
    // stage K [64][32] as bf16
    {
      long tok = (long)(kb * 64 + skey) * 32 + b2;
      const float* kp = K2 + tok * 256 + hh * 32 + sd0;
      float4 a = *(const float4*)kp;
      float4 b = *(const float4*)(kp + 4);
      short8 s;
      s[0] = f2bf(a.x); s[1] = f2bf(a.y); s[2] = f2bf(a.z); s[3] = f2bf(a.w);
      s[4] = f2bf(b.x); s[5] = f2bf(b.y); s[6] = f2bf(b.z); s[7] = f2bf(b.w);
      *(short8*)&Ks[skey][sd0] = s;
    }
    // stage V^T [32][pi(64)] as bf16
    {
      long tok = (long)(kb * 64 + vkey) * 32 + b2;
      const float* vp = V2 + tok * 256 + hh * 32 + vd0;
      float4 a = *(const float4*)vp;
      float4 b = *(const float4*)(vp + 4);
      Vt[vd0 + 0][vcol] = f2bf(a.x);
      Vt[vd0 + 1][vcol] = f2bf(a.y);
      Vt[vd0 + 2][vcol] = f2bf(a.z);
      Vt[vd0 + 3][vcol] = f2bf(a.w);
      Vt[vd0 + 4][vcol] = f2bf(b.x);
      Vt[vd0 + 5][vcol] = f2bf(b.y);
      Vt[vd0 + 6][vcol] = f2bf(b.z);
      Vt[vd0 + 7][vcol] = f2bf(b.w);
    }
    __syncthreads();
    // S = Q K^T : 4 tiles of 16 keys
    floatx4 st[4];
#pragma unroll
    for (int kt = 0; kt < 4; ++kt) {
      short8 kf = *(const short8*)&Ks[kt * 16 + l15][quad * 8];
      st[kt] = __builtin_amdgcn_mfma_f32_16x16x32_bf16(qf, kf, (floatx4)(0.f), 0, 0, 0);
    }
    // online softmax per q-row r (row = quad*4+r; cols spread over l15 x kt)
#pragma unroll
    for (int r = 0; r < 4; ++r) {
      float s0 = st[0][r] * SCALE_D32;
      float s1 = st[1][r] * SCALE_D32;
      float s2 = st[2][r] * SCALE_D32;
      float s3 = st[3][r] * SCALE_D32;
      float rm = fmaxf(fmaxf(s0, s1), fmaxf(s2, s3));
      rm = fmaxf(rm, __shfl_xor(rm, 1, 64));
      rm = fmaxf(rm, __shfl_xor(rm, 2, 64));
      rm = fmaxf(rm, __shfl_xor(rm, 4, 64));
      rm = fmaxf(rm, __shfl_xor(rm, 8, 64));
      float mnew = fmaxf(mi[r], rm);
      float al = __expf(mi[r] - mnew);
      float p0 = __expf(s0 - mnew);
      float p1 = __expf(s1 - mnew);
      float p2 = __expf(s2 - mnew);
      float p3 = __expf(s3 - mnew);
      float rs = p0 + p1 + p2 + p3;
      rs += __shfl_xor(rs, 1, 64);
      rs += __shfl_xor(rs, 2, 64);
      rs += __shfl_xor(rs, 4, 64);
      rs += __shfl_xor(rs, 8, 64);
      li[r] = li[r] * al + rs;
      mi[r] = mnew;
      Oa[r] *= al;
      Ob[r] *= al;
      short4v pp;
      pp.x = f2bf(p0); pp.y = f2bf(p1); pp.z = f2bf(p2); pp.w = f2bf(p3);
      // P[q=quad*4+r][pi(kt*16+l15)] ; pi cols for kt=0..3 are 4*l15..4*l15+3
      *(short4v*)&Pw[wave][quad * 4 + r][l15 * 4] = pp;
    }
    // PV: O[16q][32d] += P[16q][64k] V[64k][32d]  (k in pi-order both sides)
#pragma unroll
    for (int kk = 0; kk < 2; ++kk) {
      short8 pf = *(const short8*)&Pw[wave][l15][kk * 32 + quad * 8];
      short8 v0 = *(const short8*)&Vt[l15][kk * 32 + quad * 8];
      short8 v1 = *(const short8*)&Vt[16 + l15][kk * 32 + quad * 8];
      Oa = __builtin_amdgcn_mfma_f32_16x16x32_bf16(pf, v0, Oa, 0, 0, 0);
      Ob = __builtin_amdgcn_mfma_f32_16x16x32_bf16(pf, v1, Ob, 0, 0, 0);
    }
  }
  // epilogue: O row = q = quad*4+r, col = d = l15 (+16)
#pragma unroll
  for (int r = 0; r < 4; ++r) {
    float inv = 1.f / li[r];
    long tok = (long)(qblk * 64 + wave * 16 + quad * 4 + r) * 32 + b2;
    long a = tok * 256 + hh * 32 + l15;
    O2[a] = Oa[r] * inv;
    O2[a + 16] = Ob[r] * inv;
  }
}

// ---------------- row-permute m1 -> m2, fold +pos for stage-2 q/k input -----
__global__ __launch_bounds__(256) void perm12_kernel(
    const float4* __restrict__ V1o, const float4* __restrict__ Xp,
    float4* __restrict__ X2, float4* __restrict__ V2in) {
  int g = blockIdx.x * 256 + threadIdx.x;
  int m1 = g >> 6, seg = g & 63;
  int l1 = m1 >> 9, b1 = m1 & 511;
  int t = l1 >> 4, bh = (l1 >> 2) & 3, bw = l1 & 3;
  int n = b1 >> 8, ii = (b1 >> 4) & 15, j = b1 & 15;
  int l2 = t * 256 + ii * 16 + j;
  int b2 = n * 16 + bh * 4 + bw;
  int m2 = l2 * 32 + b2;
  float4 v = V1o[g];
  float4 p = Xp[g];
  float4 x;
  x.x = v.x + p.x;
  x.y = v.y + p.y;
  x.z = v.z + p.z;
  x.w = v.w + p.w;
  X2[m2 * 64 + seg] = x;
  V2in[m2 * 64 + seg] = v;
}

// ---------------- unpack: [16384,256] (m2-order) -> out [n,c,t,h,w] ---------
__global__ __launch_bounds__(256) void unpack_kernel(
    const float* __restrict__ Y, float* __restrict__ out) {
  __shared__ float tl[64][65];
  int b = blockIdx.x;
  int cb = b & 3;
  int h = (b >> 2) & 63;
  int nt = b >> 8;
  int n = nt >> 1, t = nt & 1;
  int c0 = cb * 64;
  int bh = h >> 4, ii = h & 15;
  int tx = threadIdx.x & 63;
  int ty = threadIdx.x >> 6;
  for (int ww = ty; ww < 64; ww += 4) {
    int bw = ww >> 4, j = ww & 15;
    int l2 = t * 256 + ii * 16 + j;
    int b2 = n * 16 + bh * 4 + bw;
    int m2 = l2 * 32 + b2;
    tl[tx][ww] = Y[(long)m2 * 256 + c0 + tx];
  }
  __syncthreads();
  long ob = (long)n * 2097152 + (long)t * 4096 + (long)h * 64 + tx;
  for (int cc = ty; cc < 64; cc += 4) {
    out[ob + (long)(c0 + cc) * 8192] = tl[cc][tx];
  }
}

extern "C" void kernel_launch(void* const* d_in, const int* in_sizes, int n_in,
                              void* d_out, int out_size, void* d_ws, size_t ws_size,
                              hipStream_t stream) {
  const float* q      = (const float*)d_in[0];
  const float* k      = (const float*)d_in[1];
  const float* v      = (const float*)d_in[2];
  const float* pos    = (const float*)d_in[3];
  const float* wl_in  = (const float*)d_in[4];
  const float* bl_in  = (const float*)d_in[5];
  const float* wl_out = (const float*)d_in[6];
  const float* bl_out = (const float*)d_in[7];
  const float* ws_in  = (const float*)d_in[8];
  const float* bs_in  = (const float*)d_in[9];
  const float* ws_out = (const float*)d_in[10];
  const float* bs_out = (const float*)d_in[11];
  float* out = (float*)d_out;
  float* ws = (float*)d_ws;
  const size_t SL = 4194304;  // floats per 16 MB slot (16384 x 256)
  float* s0 = ws;            // Xp
  float* s1 = ws + SL;       // Xq -> O1 -> V2
  float* s2 = ws + 2 * SL;   // Xk -> V1o -> Yfinal
  float* s3 = ws + 3 * SL;   // Xv -> X2 -> O2
  float* s4 = ws + 4 * SL;   // Q1 -> V2in
  float* s5 = ws + 5 * SL;   // K1 -> Q2
  float* s6 = ws + 6 * SL;   // V1 -> K2

  pack_kernel<<<1024, 256, 0, stream>>>(q, k, v, pos, s0, s1, s2, s3);

  dim3 gg(128, 4);  // 128 M-blocks x 4 N-blocks, tile 128x64
  gemm_mfma<<<gg, 256, 0, stream>>>(s1, wl_in,          bl_in,       s4);  // Q1
  gemm_mfma<<<gg, 256, 0, stream>>>(s2, wl_in + 65536,  bl_in + 256, s5);  // K1
  gemm_mfma<<<gg, 256, 0, stream>>>(s3, wl_in + 131072, bl_in + 512, s6);  // V1

  attn1_kernel<<<4096, 64, 0, stream>>>(s4, s5, s6, s1);                 // O1 -> s1
  gemm_mfma<<<gg, 256, 0, stream>>>(s1, wl_out, bl_out, s2);             // V1o -> s2

  perm12_kernel<<<4096, 256, 0, stream>>>((const float4*)s2, (const float4*)s0,
                                          (float4*)s3, (float4*)s4);     // X2->s3, v2->s4

  gemm_mfma<<<gg, 256, 0, stream>>>(s3, ws_in,          bs_in,       s5);  // Q2
  gemm_mfma<<<gg, 256, 0, stream>>>(s3, ws_in + 65536,  bs_in + 256, s6);  // K2
  gemm_mfma<<<gg, 256, 0, stream>>>(s4, ws_in + 131072, bs_in + 512, s1);  // V2

  attn2_mfma<<<2048, 256, 0, stream>>>(s5, s6, s1, s3);                  // O2 -> s3
  gemm_mfma<<<gg, 256, 0, stream>>>(s3, ws_out, bs_out, s2);             // Yfinal -> s2

  unpack_kernel<<<1024, 256, 0, stream>>>(s2, out);
}

// Round 4
// 331.906 us; speedup vs baseline: 1.8692x; 1.1969x over previous
//
#include <hip/hip_runtime.h>
#include <math.h>

// Problem constants: n=2, c=256, t=2, h=64, w=64; HB=WB=16, bn_h=bn_w=4;
// NHEAD=8, d=32. Stage1: L1=32 tokens x B1=512 batch. Stage2: L2=512 x B2=32.
// Token id m1 = l1*512 + b1, l1=(t*4+bh)*4+bw, b1=n*256+i*16+j.
// Token id m2 = l2*32 + b2,  l2=t*256+i*16+j,  b2=n*16+bh*4+bw.
// Input/out layout [n,c,t,h,w]: flat = n*2097152 + c*8192 + t*4096 + h*64 + w.
// R4: all intermediates bf16 (producer-side rounding — bit-identical MFMA
// inputs vs R3's consumer-side rounding); final GEMM writes fp32.

#define SCALE_D32 0.17677669529663687f  // 1/sqrt(32)

typedef short short8 __attribute__((ext_vector_type(8)));   // 8 bf16 = 16B
typedef short short4v __attribute__((ext_vector_type(4)));  // 4 bf16 = 8B
typedef float floatx4 __attribute__((ext_vector_type(4)));  // MFMA C/D frag

__device__ __forceinline__ short f2bf(float f) {
  union { float f; unsigned u; } x;
  x.f = f;
  unsigned r = x.u + 0x7fffu + ((x.u >> 16) & 1u);  // RNE
  return (short)(r >> 16);
}
__device__ __forceinline__ float bf2f(short s) {
  union { unsigned u; float f; } x;
  x.u = ((unsigned)(unsigned short)s) << 16;
  return x.f;
}

// ---------------- pack: [n,c,t,h,w] fp32 -> token-major [16384,256] bf16 ----
__global__ __launch_bounds__(256) void pack_kernel(
    const float* __restrict__ q, const float* __restrict__ k,
    const float* __restrict__ v, const float* __restrict__ pos,
    short* __restrict__ Xp, short* __restrict__ Xq,
    short* __restrict__ Xk, short* __restrict__ Xv) {
  __shared__ float tP[64][65];
  __shared__ float tX[64][65];
  int b = blockIdx.x;
  int cb = b & 3;
  int h  = (b >> 2) & 63;
  int nt = b >> 8;
  int n = nt >> 1, t = nt & 1;
  int c0 = cb * 64;
  int bh = h >> 4, ii = h & 15;
  long inbase = (long)n * 2097152 + (long)t * 4096 + (long)h * 64;
  int tx = threadIdx.x & 63;
  int ty = threadIdx.x >> 6;  // 0..3

  for (int cc = ty; cc < 64; cc += 4) {
    long a = inbase + (long)(c0 + cc) * 8192 + tx;
    tP[cc][tx] = pos[a];
    tX[cc][tx] = q[a];
  }
  __syncthreads();
  for (int ww = ty; ww < 64; ww += 4) {
    int bw = ww >> 4, j = ww & 15;
    int m1 = (((t * 4 + bh) * 4 + bw) * 512) + n * 256 + ii * 16 + j;
    long o = (long)m1 * 256 + c0 + tx;
    float pv = tP[tx][ww];
    Xp[o] = f2bf(pv);
    Xq[o] = f2bf(tX[tx][ww] + pv);
  }
  __syncthreads();
  for (int cc = ty; cc < 64; cc += 4) {
    long a = inbase + (long)(c0 + cc) * 8192 + tx;
    tX[cc][tx] = k[a];
  }
  __syncthreads();
  for (int ww = ty; ww < 64; ww += 4) {
    int bw = ww >> 4, j = ww & 15;
    int m1 = (((t * 4 + bh) * 4 + bw) * 512) + n * 256 + ii * 16 + j;
    long o = (long)m1 * 256 + c0 + tx;
    Xk[o] = f2bf(tX[tx][ww] + tP[tx][ww]);
  }
  __syncthreads();
  for (int cc = ty; cc < 64; cc += 4) {
    long a = inbase + (long)(c0 + cc) * 8192 + tx;
    tX[cc][tx] = v[a];
  }
  __syncthreads();
  for (int ww = ty; ww < 64; ww += 4) {
    int bw = ww >> 4, j = ww & 15;
    int m1 = (((t * 4 + bh) * 4 + bw) * 512) + n * 256 + ii * 16 + j;
    long o = (long)m1 * 256 + c0 + tx;
    Xv[o] = f2bf(tX[tx][ww]);
  }
}

// ------- bf16 MFMA TN GEMM: C[M,256] = A[M,256](bf16) @ W[256,256]^T + b ----
// W is fp32 (weights), converted during staging. OUT32 selects fp32/bf16 C.
// grid (128, 4) tile 128x64; A-tile re-readers share bid%8 -> same XCD L2.
template <bool OUT32>
__global__ __launch_bounds__(256) void gemm_mfma(
    const short* __restrict__ A, const float* __restrict__ Wt,
    const float* __restrict__ bias, void* __restrict__ Cout) {
  __shared__ short As[128][72];
  __shared__ short Ws[64][72];
  int m0 = blockIdx.x * 128;
  int n0 = blockIdx.y * 64;
  int tid = threadIdx.x;
  int lane = tid & 63;
  int wave = tid >> 6;
  int wm = wave >> 1;
  int wn = wave & 1;
  int l15 = lane & 15;
  int quad = lane >> 4;

  int srowA = tid >> 3;   // 0..31 (A staging: 32 rows/pass, 8x short8 per row)
  int scol8 = tid & 7;
  int srowW = tid >> 4;   // 0..15 (W staging)
  int scol4 = tid & 15;

  floatx4 acc[4][2];
#pragma unroll
  for (int mt = 0; mt < 4; ++mt)
#pragma unroll
    for (int nt = 0; nt < 2; ++nt)
      acc[mt][nt] = (floatx4)(0.f);

  for (int kb = 0; kb < 4; ++kb) {
    int k0 = kb * 64;
    if (kb) __syncthreads();
#pragma unroll
    for (int p = 0; p < 4; ++p) {  // A: 4 passes x 32 rows, bf16 passthrough
      int row = p * 32 + srowA;
      *(short8*)&As[row][scol8 * 8] =
          *(const short8*)(A + (long)(m0 + row) * 256 + k0 + scol8 * 8);
    }
#pragma unroll
    for (int p = 0; p < 4; ++p) {  // W: fp32 -> bf16
      int row = p * 16 + srowW;
      float4 wv = *(const float4*)(Wt + (long)(n0 + row) * 256 + k0 + scol4 * 4);
      short4v sv;
      sv.x = f2bf(wv.x); sv.y = f2bf(wv.y); sv.z = f2bf(wv.z); sv.w = f2bf(wv.w);
      *(short4v*)&Ws[row][scol4 * 4] = sv;
    }
    __syncthreads();
#pragma unroll
    for (int ks = 0; ks < 2; ++ks) {
      short8 af[4], bfr[2];
#pragma unroll
      for (int mt = 0; mt < 4; ++mt)
        af[mt] = *(const short8*)&As[wm * 64 + mt * 16 + l15][ks * 32 + quad * 8];
#pragma unroll
      for (int nt = 0; nt < 2; ++nt)
        bfr[nt] = *(const short8*)&Ws[wn * 32 + nt * 16 + l15][ks * 32 + quad * 8];
#pragma unroll
      for (int mt = 0; mt < 4; ++mt)
#pragma unroll
        for (int nt = 0; nt < 2; ++nt)
          acc[mt][nt] = __builtin_amdgcn_mfma_f32_16x16x32_bf16(
              af[mt], bfr[nt], acc[mt][nt], 0, 0, 0);
    }
  }
  float b0 = bias[n0 + wn * 32 + l15];
  float b1 = bias[n0 + wn * 32 + 16 + l15];
#pragma unroll
  for (int mt = 0; mt < 4; ++mt) {
#pragma unroll
    for (int r = 0; r < 4; ++r) {
      int row = m0 + wm * 64 + mt * 16 + quad * 4 + r;
      long base = (long)row * 256 + n0 + wn * 32 + l15;
      if (OUT32) {
        float* C = (float*)Cout;
        C[base] = acc[mt][0][r] + b0;
        C[base + 16] = acc[mt][1][r] + b1;
      } else {
        short* C = (short*)Cout;
        C[base] = f2bf(acc[mt][0][r] + b0);
        C[base + 16] = f2bf(acc[mt][1][r] + b1);
      }
    }
  }
}

// ---------------- stage-1 attention: L=32, d=32, per-wave (b1, head) --------
// bf16 in/out, fp32 compute (convert at stage).
__global__ __launch_bounds__(64) void attn1_kernel(
    const short* __restrict__ Q1, const short* __restrict__ K1,
    const short* __restrict__ V1, short* __restrict__ O1) {
  __shared__ float Qs[32][36];
  __shared__ float Ks[32][36];
  __shared__ float Vs[32][36];
  int b1 = blockIdx.x >> 3;
  int hh = blockIdx.x & 7;
  int lane = threadIdx.x;
  for (int idx = lane; idx < 128; idx += 64) {
    int row = idx >> 2, seg = idx & 3;  // 8 bf16 per seg
    long a = ((long)row * 512 + b1) * 256 + hh * 32 + seg * 8;
    short8 qv = *(const short8*)&Q1[a];
    short8 kv = *(const short8*)&K1[a];
    short8 vv = *(const short8*)&V1[a];
#pragma unroll
    for (int j = 0; j < 8; ++j) {
      Qs[row][seg * 8 + j] = bf2f(qv[j]);
      Ks[row][seg * 8 + j] = bf2f(kv[j]);
      Vs[row][seg * 8 + j] = bf2f(vv[j]);
    }
  }
  __syncthreads();
  int lq = lane & 31, half = lane >> 5;
  float qreg[32];
#pragma unroll
  for (int s8 = 0; s8 < 8; ++s8) {
    float4 qv = *(const float4*)&Qs[lq][s8 * 4];
    qreg[s8 * 4 + 0] = qv.x;
    qreg[s8 * 4 + 1] = qv.y;
    qreg[s8 * 4 + 2] = qv.z;
    qreg[s8 * 4 + 3] = qv.w;
  }
  float sc[16];
#pragma unroll
  for (int z = 0; z < 16; ++z) {
    int lk = half * 16 + z;
    float d = 0.f;
#pragma unroll
    for (int s8 = 0; s8 < 8; ++s8) {
      float4 kv = *(const float4*)&Ks[lk][s8 * 4];
      d += qreg[s8 * 4 + 0] * kv.x + qreg[s8 * 4 + 1] * kv.y +
           qreg[s8 * 4 + 2] * kv.z + qreg[s8 * 4 + 3] * kv.w;
    }
    sc[z] = d * SCALE_D32;
  }
  float mymax = sc[0];
#pragma unroll
  for (int z = 1; z < 16; ++z) mymax = fmaxf(mymax, sc[z]);
  float omax = __shfl_xor(mymax, 32, 64);
  float gm = fmaxf(mymax, omax);
  float ssum = 0.f;
#pragma unroll
  for (int z = 0; z < 16; ++z) {
    sc[z] = __expf(sc[z] - gm);
    ssum += sc[z];
  }
  float osum = __shfl_xor(ssum, 32, 64);
  float inv = 1.f / (ssum + osum);
  float o[32] = {};
#pragma unroll
  for (int z = 0; z < 16; ++z) {
    int lk = half * 16 + z;
    float p = sc[z];
#pragma unroll
    for (int s8 = 0; s8 < 8; ++s8) {
      float4 vv = *(const float4*)&Vs[lk][s8 * 4];
      o[s8 * 4 + 0] += p * vv.x;
      o[s8 * 4 + 1] += p * vv.y;
      o[s8 * 4 + 2] += p * vv.z;
      o[s8 * 4 + 3] += p * vv.w;
    }
  }
#pragma unroll
  for (int dd = 0; dd < 32; ++dd) o[dd] += __shfl_xor(o[dd], 32, 64);
  long ob = ((long)lq * 512 + b1) * 256 + hh * 32;
  int doff = half * 16;
  if (lane < 32 || half == 1) {  // both halves store their 16 cols
#pragma unroll
    for (int s4 = 0; s4 < 4; ++s4) {
      short4v r;
      r.x = f2bf(o[doff + s4 * 4 + 0] * inv);
      r.y = f2bf(o[doff + s4 * 4 + 1] * inv);
      r.z = f2bf(o[doff + s4 * 4 + 2] * inv);
      r.w = f2bf(o[doff + s4 * 4 + 3] * inv);
      *(short4v*)&O1[ob + doff + s4 * 4] = r;
    }
  }
}

// ---------------- stage-2 attention: MFMA flash, L=512, d=32, bf16 ----------
// grid 2048: bid = qblk*256 + g, g = b2*8+hh -> the 8 qblk blocks of a group
// share bid%8 (same XCD under round-robin) so K/V are fetched once per XCD.
__global__ __launch_bounds__(256) void attn2_mfma(
    const short* __restrict__ Q2, const short* __restrict__ K2,
    const short* __restrict__ V2, short* __restrict__ O2) {
  __shared__ short Ks[64][40];      // [key][d]
  __shared__ short Vt[32][72];      // [d][pi(key)]
  __shared__ short Pw[4][16][72];   // per-wave [q][pi(key)]
  int bid = blockIdx.x;
  int g = bid & 255;
  int qblk = bid >> 8;
  int hh = g & 7;
  int b2 = g >> 3;
  int tid = threadIdx.x;
  int wave = tid >> 6, lane = tid & 63;
  int l15 = lane & 15, quad = lane >> 4;

  // Q fragment: m = l15 -> q row; k = quad*8+j -> d  (16B direct load)
  short8 qf;
  {
    long tok = (long)(qblk * 64 + wave * 16 + l15) * 32 + b2;
    qf = *(const short8*)(Q2 + tok * 256 + hh * 32 + quad * 8);
  }
  floatx4 Oa = (floatx4)(0.f), Ob = (floatx4)(0.f);
  float mi[4], li[4];
#pragma unroll
  for (int r = 0; r < 4; ++r) { mi[r] = -1e30f; li[r] = 0.f; }

  int skey = tid >> 2;          // K staging: 0..63
  int sd0 = (tid & 3) * 8;
  int vkey = lane;              // V staging
  int vd0 = wave * 8;
  int vcol = (vkey & 15) * 4 + (vkey >> 4);  // pi(key)

  for (int kb = 0; kb < 8; ++kb) {
    if (kb) __syncthreads();
    {  // stage K [64][32] bf16 passthrough
      long tok = (long)(kb * 64 + skey) * 32 + b2;
      *(short8*)&Ks[skey][sd0] = *(const short8*)(K2 + tok * 256 + hh * 32 + sd0);
    }
    {  // stage V^T [32][pi(64)] bf16 passthrough
      long tok = (long)(kb * 64 + vkey) * 32 + b2;
      short8 v = *(const short8*)(V2 + tok * 256 + hh * 32 + vd0);
#pragma unroll
      for (int j = 0; j < 8; ++j) Vt[vd0 + j][vcol] = v[j];
    }
    __syncthreads();
    floatx4 st[4];
#pragma unroll
    for (int kt = 0; kt < 4; ++kt) {
      short8 kf = *(const short8*)&Ks[kt * 16 + l15][quad * 8];
      st[kt] = __builtin_amdgcn_mfma_f32_16x16x32_bf16(qf, kf, (floatx4)(0.f), 0, 0, 0);
    }
#pragma unroll
    for (int r = 0; r < 4; ++r) {
      float s0 = st[0][r] * SCALE_D32;
      float s1 = st[1][r] * SCALE_D32;
      float s2 = st[2][r] * SCALE_D32;
      float s3 = st[3][r] * SCALE_D32;
      float rm = fmaxf(fmaxf(s0, s1), fmaxf(s2, s3));
      rm = fmaxf(rm, __shfl_xor(rm, 1, 64));
      rm = fmaxf(rm, __shfl_xor(rm, 2, 64));
      rm = fmaxf(rm, __shfl_xor(rm, 4, 64));
      rm = fmaxf(rm, __shfl_xor(rm, 8, 64));
      float mnew = fmaxf(mi[r], rm);
      float al = __expf(mi[r] - mnew);
      float p0 = __expf(s0 - mnew);
      float p1 = __expf(s1 - mnew);
      float p2 = __expf(s2 - mnew);
      float p3 = __expf(s3 - mnew);
      float rs = p0 + p1 + p2 + p3;
      rs += __shfl_xor(rs, 1, 64);
      rs += __shfl_xor(rs, 2, 64);
      rs += __shfl_xor(rs, 4, 64);
      rs += __shfl_xor(rs, 8, 64);
      li[r] = li[r] * al + rs;
      mi[r] = mnew;
      Oa[r] *= al;
      Ob[r] *= al;
      short4v pp;
      pp.x = f2bf(p0); pp.y = f2bf(p1); pp.z = f2bf(p2); pp.w = f2bf(p3);
      *(short4v*)&Pw[wave][quad * 4 + r][l15 * 4] = pp;
    }
#pragma unroll
    for (int kk = 0; kk < 2; ++kk) {
      short8 pf = *(const short8*)&Pw[wave][l15][kk * 32 + quad * 8];
      short8 v0 = *(const short8*)&Vt[l15][kk * 32 + quad * 8];
      short8 v1 = *(const short8*)&Vt[16 + l15][kk * 32 + quad * 8];
      Oa = __builtin_amdgcn_mfma_f32_16x16x32_bf16(pf, v0, Oa, 0, 0, 0);
      Ob = __builtin_amdgcn_mfma_f32_16x16x32_bf16(pf, v1, Ob, 0, 0, 0);
    }
  }
#pragma unroll
  for (int r = 0; r < 4; ++r) {
    float inv = 1.f / li[r];
    long tok = (long)(qblk * 64 + wave * 16 + quad * 4 + r) * 32 + b2;
    long a = tok * 256 + hh * 32 + l15;
    O2[a] = f2bf(Oa[r] * inv);
    O2[a + 16] = f2bf(Ob[r] * inv);
  }
}

// ---------------- row-permute m1 -> m2, fold +pos (all bf16) ----------------
__global__ __launch_bounds__(256) void perm12_kernel(
    const short8* __restrict__ V1o, const short8* __restrict__ Xp,
    short8* __restrict__ X2, short8* __restrict__ V2in) {
  int gg = blockIdx.x * 256 + threadIdx.x;  // 0 .. 524287 (short8 units)
  int m1 = gg >> 5, seg = gg & 31;
  int l1 = m1 >> 9, b1 = m1 & 511;
  int t = l1 >> 4, bh = (l1 >> 2) & 3, bw = l1 & 3;
  int n = b1 >> 8, ii = (b1 >> 4) & 15, j = b1 & 15;
  int l2 = t * 256 + ii * 16 + j;
  int b2 = n * 16 + bh * 4 + bw;
  int m2 = l2 * 32 + b2;
  short8 v = V1o[gg];
  short8 p = Xp[gg];
  short8 x;
#pragma unroll
  for (int jj = 0; jj < 8; ++jj) x[jj] = f2bf(bf2f(v[jj]) + bf2f(p[jj]));
  X2[m2 * 32 + seg] = x;
  V2in[m2 * 32 + seg] = v;
}

// ---------------- unpack: [16384,256] fp32 (m2-order) -> out [n,c,t,h,w] ----
__global__ __launch_bounds__(256) void unpack_kernel(
    const float* __restrict__ Y, float* __restrict__ out) {
  __shared__ float tl[64][65];
  int b = blockIdx.x;
  int cb = b & 3;
  int h = (b >> 2) & 63;
  int nt = b >> 8;
  int n = nt >> 1, t = nt & 1;
  int c0 = cb * 64;
  int bh = h >> 4, ii = h & 15;
  int tx = threadIdx.x & 63;
  int ty = threadIdx.x >> 6;
  for (int ww = ty; ww < 64; ww += 4) {
    int bw = ww >> 4, j = ww & 15;
    int l2 = t * 256 + ii * 16 + j;
    int b2 = n * 16 + bh * 4 + bw;
    int m2 = l2 * 32 + b2;
    tl[tx][ww] = Y[(long)m2 * 256 + c0 + tx];
  }
  __syncthreads();
  long ob = (long)n * 2097152 + (long)t * 4096 + (long)h * 64 + tx;
  for (int cc = ty; cc < 64; cc += 4) {
    out[ob + (long)(c0 + cc) * 8192] = tl[cc][tx];
  }
}

extern "C" void kernel_launch(void* const* d_in, const int* in_sizes, int n_in,
                              void* d_out, int out_size, void* d_ws, size_t ws_size,
                              hipStream_t stream) {
  const float* q      = (const float*)d_in[0];
  const float* k      = (const float*)d_in[1];
  const float* v      = (const float*)d_in[2];
  const float* pos    = (const float*)d_in[3];
  const float* wl_in  = (const float*)d_in[4];
  const float* bl_in  = (const float*)d_in[5];
  const float* wl_out = (const float*)d_in[6];
  const float* bl_out = (const float*)d_in[7];
  const float* ws_in  = (const float*)d_in[8];
  const float* bs_in  = (const float*)d_in[9];
  const float* ws_out = (const float*)d_in[10];
  const float* bs_out = (const float*)d_in[11];
  float* out = (float*)d_out;
  char* wsb = (char*)d_ws;
  const size_t SLB = 16777216;  // 16 MB per slot (bf16 tensors use half)
  short* s0 = (short*)(wsb);            // Xp
  short* s1 = (short*)(wsb + SLB);      // Xq -> O1 -> V2
  short* s2 = (short*)(wsb + 2 * SLB);  // Xk -> V1o -> Yfinal(fp32)
  short* s3 = (short*)(wsb + 3 * SLB);  // Xv -> X2 -> O2
  short* s4 = (short*)(wsb + 4 * SLB);  // Q1 -> V2in
  short* s5 = (short*)(wsb + 5 * SLB);  // K1 -> Q2
  short* s6 = (short*)(wsb + 6 * SLB);  // V1 -> K2

  pack_kernel<<<1024, 256, 0, stream>>>(q, k, v, pos, s0, s1, s2, s3);

  dim3 gg(128, 4);
  gemm_mfma<false><<<gg, 256, 0, stream>>>(s1, wl_in,          bl_in,       s4);  // Q1
  gemm_mfma<false><<<gg, 256, 0, stream>>>(s2, wl_in + 65536,  bl_in + 256, s5);  // K1
  gemm_mfma<false><<<gg, 256, 0, stream>>>(s3, wl_in + 131072, bl_in + 512, s6);  // V1

  attn1_kernel<<<4096, 64, 0, stream>>>(s4, s5, s6, s1);                   // O1 -> s1
  gemm_mfma<false><<<gg, 256, 0, stream>>>(s1, wl_out, bl_out, s2);        // V1o -> s2

  perm12_kernel<<<2048, 256, 0, stream>>>((const short8*)s2, (const short8*)s0,
                                          (short8*)s3, (short8*)s4);       // X2->s3, V2in->s4

  gemm_mfma<false><<<gg, 256, 0, stream>>>(s3, ws_in,          bs_in,       s5);  // Q2
  gemm_mfma<false><<<gg, 256, 0, stream>>>(s3, ws_in + 65536,  bs_in + 256, s6);  // K2
  gemm_mfma<false><<<gg, 256, 0, stream>>>(s4, ws_in + 131072, bs_in + 512, s1);  // V2

  attn2_mfma<<<2048, 256, 0, stream>>>(s5, s6, s1, s3);                    // O2 -> s3
  gemm_mfma<true><<<gg, 256, 0, stream>>>(s3, ws_out, bs_out, s2);         // Y(fp32) -> s2

  unpack_kernel<<<1024, 256, 0, stream>>>((const float*)s2, out);
}